// Round 11
// baseline (251.759 us; speedup 1.0000x reference)
//
#include <hip/hip_runtime.h>
#include <hip/hip_bf16.h>
#include <math.h>

// N = 100000, E = 3.2M, F_in = 128, H = C = 16. int inputs arrive as int32.
//
// out[d] = dinv[d]*(sum_{s->d} u[s] + u[d]) + b,  u = dinv .* (h @ W).
// R3: global f32 atomics ~19.5G txn/s. R5: LDS f32 atomics ~3cy/lane.
// R6: sort->CSR->register gather. R7: bf16 messages. R8: 2-pass radix bin.
// R9: XCD swizzle. R10: pipelined gathers = 242us (gf ~43us each, plateau).
// R11: single-pass binning into static per-bucket regions (kills histA +
//      colscan + hist_t traffic + 2 launches); bucket totals via global
//      reservation cursors; dense CSR produced by sortcsr as before.

#define F_IN 128
#define H 16
#define NPB 128            // nodes per bucket
#define MAX_NB 800         // max buckets (N <= 102400)
#define NBLK 256           // binning blocks
#define BINT 1024          // binning threads per block
#define SMAX 4864          // max edges per bucket region (mean 4096, +12 sigma)
#define PFD 6              // gather prefetch depth: 8 slots * 6 = 48 edges

typedef __hip_bfloat16 bf16;

__device__ __forceinline__ float bflo(unsigned v) { return __uint_as_float(v << 16); }
__device__ __forceinline__ float bfhi(unsigned v) { return __uint_as_float(v & 0xffff0000u); }

// physical block -> logical block so logically-adjacent blocks (adjacent output
// runs in packed[]) land on the same XCD (XCD = physical % 8 round-robin).
__device__ __forceinline__ int swz(int p) { return (p & 7) * 32 + (p >> 3); }

// ---- single-pass binning: LDS hist of chunk -> global range reservation ->
//      place edges into packed[bucket*SMAX + loc]. packed = (dst&127)<<17|src.
__global__ void bin1_kernel(const int* __restrict__ src, const int* __restrict__ dst,
                            int* __restrict__ gcursor, unsigned* __restrict__ packed,
                            int E, int NB) {
    __shared__ int h[MAX_NB];
    __shared__ int pos[MAX_NB];
    int b = swz(blockIdx.x);
    long long e0 = (long long)E * b / NBLK;
    long long e1 = (long long)E * (b + 1) / NBLK;
    for (int i = threadIdx.x; i < NB; i += BINT) h[i] = 0;
    __syncthreads();
    for (long long e = e0 + threadIdx.x; e < e1; e += BINT)
        atomicAdd(&h[dst[e] >> 7], 1);
    __syncthreads();
    for (int i = threadIdx.x; i < NB; i += BINT) {
        int c = h[i];
        pos[i] = (c > 0) ? atomicAdd(&gcursor[i], c) : 0;
    }
    __syncthreads();
    for (long long e = e0 + threadIdx.x; e < e1; e += BINT) {
        int d = dst[e];
        int bk = d >> 7;
        int loc = atomicAdd(&pos[bk], 1);
        if (loc < SMAX)
            packed[(size_t)bk * SMAX + loc] = (unsigned)src[e] | ((unsigned)(d & 127) << 17);
    }
}

// ---- exclusive scan over bucket totals -> base[] (dense CSR bases) ----
__global__ void bucketscan_kernel(const int* __restrict__ gcursor, int* __restrict__ base, int NB) {
    __shared__ int s[1024];
    int t = threadIdx.x;
    int v = 0;
    if (t < NB) { v = gcursor[t]; if (v > SMAX) v = SMAX; }
    s[t] = v;
    __syncthreads();
    for (int off = 1; off < 1024; off <<= 1) {
        int w = (t >= off) ? s[t - off] : 0;
        __syncthreads();
        s[t] += w;
        __syncthreads();
    }
    if (t < NB) base[t] = s[t] - v;
    if (t == NB - 1) base[NB] = s[t];
}

// ---- per-bucket LDS counting sort: packed region -> dense sorted[], rowptr[], dinv[] ----
__global__ void sortcsr_kernel(const unsigned* __restrict__ packed, const int* __restrict__ gcursor,
                               const int* __restrict__ base, unsigned* __restrict__ sorted,
                               int* __restrict__ rowptr, float* __restrict__ dinv, int N) {
    __shared__ unsigned ssort[SMAX];
    __shared__ int cnt[NPB], offs[NPB], cur[NPB];
    int b = blockIdx.x;
    int rp = b * SMAX;                 // read position (padded regions)
    int len = gcursor[b];
    if (len > SMAX) len = SMAX;
    int e0 = base[b];                  // write position (dense)
    int T = blockDim.x;

    for (int i = threadIdx.x; i < NPB; i += T) cnt[i] = 0;
    __syncthreads();
    for (int i = threadIdx.x; i < len; i += T)
        atomicAdd(&cnt[packed[rp + i] >> 17], 1);
    __syncthreads();
    if (threadIdx.x < NPB) offs[threadIdx.x] = cnt[threadIdx.x];
    __syncthreads();
    for (int off = 1; off < NPB; off <<= 1) {
        int v = 0;
        if (threadIdx.x < NPB && threadIdx.x >= off) v = offs[threadIdx.x - off];
        __syncthreads();
        if (threadIdx.x < NPB) offs[threadIdx.x] += v;
        __syncthreads();
    }
    if (threadIdx.x < NPB) {
        int ex = offs[threadIdx.x] - cnt[threadIdx.x];
        cur[threadIdx.x] = ex;
        int node = b * NPB + threadIdx.x;
        if (node < N) {
            rowptr[node] = e0 + ex;
            dinv[node] = rsqrtf(1.0f + (float)cnt[threadIdx.x]);
        }
    }
    __syncthreads();
    for (int i = threadIdx.x; i < len; i += T) {
        unsigned p = packed[rp + i];
        int pos = atomicAdd(&cur[p >> 17], 1);
        ssort[pos] = p;
    }
    __syncthreads();
    for (int i = threadIdx.x; i < len; i += T) sorted[e0 + i] = ssort[i];
    if (b == 0 && threadIdx.x == 0) rowptr[N] = base[gridDim.x];
}

// ---- u[i][j] = dinv[i] * sum_k x[i][k]*W1[k][j]  (bf16 out) ----
#define XPAD 132
__global__ void xw1_kernel(const float* __restrict__ x, const float* __restrict__ W1,
                           const float* __restrict__ dinv, bf16* __restrict__ u, int n) {
    __shared__ float sW1[F_IN * H];
    __shared__ float sx[16 * XPAD];
    for (int t = threadIdx.x; t < F_IN * H; t += blockDim.x) sW1[t] = W1[t];

    int basei = blockIdx.x * 16;
    for (int idx = threadIdx.x; idx < 512; idx += 256) {
        int r = idx >> 5;
        int kk = (idx & 31) << 2;
        int row = basei + r;
        float4 v = make_float4(0.f, 0.f, 0.f, 0.f);
        if (row < n) v = *(const float4*)(x + (size_t)row * F_IN + kk);
        *(float4*)(sx + r * XPAD + kk) = v;
    }
    __syncthreads();

    int r = threadIdx.x >> 4;
    int j = threadIdx.x & 15;
    int row = basei + r;
    if (row >= n) return;

    const float* xr = sx + r * XPAD;
    float acc = 0.0f;
#pragma unroll 16
    for (int k = 0; k < F_IN; k++) acc += xr[k] * sW1[k * H + j];
    u[(size_t)row * H + j] = __float2bfloat16(dinv[row] * acc);
}

// ================= pipelined gather core (shared by both layers) =============
// lane = (ch-pair j2 0..7) x (slot g 0..7). Depth-2 pipeline over the 16 nodes
// a wave owns: prefetch sorted[t+1] while consuming uv[t] issued last iter.
#define GATHER_TILE(UVPTR)                                                      \
    int lane = threadIdx.x & 63;                                                \
    int wave = threadIdx.x >> 6;                                                \
    int j2 = lane & 7, g = lane >> 3;                                           \
    int nodeBase = blockIdx.x * 64 + wave * 16;                                 \
    int r0c = 0, r1c = 0;                                                       \
    unsigned svc[PFD]; unsigned uvc[PFD];                                       \
    {   int node = nodeBase;                                                    \
        if (node < N) { r0c = rowptr[node]; r1c = rowptr[node + 1]; }           \
        _Pragma("unroll")                                                       \
        for (int m = 0; m < PFD; m++) {                                         \
            int k = r0c + g + 8 * m;                                            \
            if (k < r1c) svc[m] = sorted[k];                                    \
        }                                                                       \
        _Pragma("unroll")                                                       \
        for (int m = 0; m < PFD; m++) {                                         \
            int k = r0c + g + 8 * m;                                            \
            if (k < r1c) uvc[m] = UVPTR[(size_t)(svc[m] & 0x1FFFF) * 8 + j2];   \
        }                                                                       \
    }                                                                           \
    for (int t = 0; t < 16; t++) {                                              \
        int r0n = 0, r1n = 0;                                                   \
        unsigned svn[PFD];                                                      \
        if (t < 15) {                                                           \
            int nn = nodeBase + t + 1;                                          \
            if (nn < N) { r0n = rowptr[nn]; r1n = rowptr[nn + 1]; }             \
            _Pragma("unroll")                                                   \
            for (int m = 0; m < PFD; m++) {                                     \
                int k = r0n + g + 8 * m;                                        \
                if (k < r1n) svn[m] = sorted[k];                                \
            }                                                                   \
        }                                                                       \
        float ax = 0.f, ay = 0.f;                                               \
        _Pragma("unroll")                                                       \
        for (int m = 0; m < PFD; m++) {                                         \
            int k = r0c + g + 8 * m;                                            \
            if (k < r1c) { ax += bflo(uvc[m]); ay += bfhi(uvc[m]); }            \
        }                                                                       \
        for (int k = r0c + g + 8 * PFD; k < r1c; k += 8) {                      \
            unsigned va = UVPTR[(size_t)(sorted[k] & 0x1FFFF) * 8 + j2];        \
            ax += bflo(va); ay += bfhi(va);                                     \
        }                                                                       \
        ax += __shfl_xor(ax, 8);  ay += __shfl_xor(ay, 8);                      \
        ax += __shfl_xor(ax, 16); ay += __shfl_xor(ay, 16);                     \
        ax += __shfl_xor(ax, 32); ay += __shfl_xor(ay, 32);                     \
        if (g == 0) {                                                           \
            tile[(wave * 16 + t) * 16 + 2 * j2] = ax;                           \
            tile[(wave * 16 + t) * 16 + 2 * j2 + 1] = ay;                       \
        }                                                                       \
        if (t < 15) {                                                           \
            r0c = r0n; r1c = r1n;                                               \
            _Pragma("unroll")                                                   \
            for (int m = 0; m < PFD; m++) {                                     \
                int k = r0n + g + 8 * m;                                        \
                svc[m] = svn[m];                                                \
                if (k < r1n) uvc[m] = UVPTR[(size_t)(svn[m] & 0x1FFFF) * 8 + j2]; \
            }                                                                   \
        }                                                                       \
    }

// ---- layer-1 gather + finalize ----
__global__ void gatherfin1_kernel(const unsigned* __restrict__ sorted, const int* __restrict__ rowptr,
                                  const bf16* __restrict__ u, const float* __restrict__ dinv,
                                  const float* __restrict__ b1, const float* __restrict__ W2,
                                  bf16* __restrict__ u2, int N) {
    __shared__ float tile[64 * 16];
    __shared__ float sW2[256];
    __shared__ float sb1[16];
    sW2[threadIdx.x] = W2[threadIdx.x];
    if (threadIdx.x < 16) sb1[threadIdx.x] = b1[threadIdx.x];

    const unsigned* uvp = (const unsigned*)u;   // [node*8 + j2] channel pairs
    GATHER_TILE(uvp)
    __syncthreads();

    int jj = threadIdx.x & 15;
    for (int rr = 0; rr < 4; rr++) {
        int rl = (threadIdx.x >> 4) + rr * 16;
        int node = blockIdx.x * 64 + rl;
        float h = 0.f, di = 0.f;
        if (node < N) {
            di = dinv[node];
            h = di * (tile[rl * 16 + jj] + __bfloat162float(u[(size_t)node * H + jj])) + sb1[jj];
            h = fmaxf(h, 0.f);
        }
        float acc2 = 0.f;
#pragma unroll
        for (int kk = 0; kk < 16; kk++) {
            float hk = __shfl(h, kk, 16);
            acc2 += hk * sW2[kk * 16 + jj];
        }
        if (node < N) u2[(size_t)node * H + jj] = __float2bfloat16(di * acc2);
    }
}

// ---- layer-2 gather + finalize: log_softmax -> out (f32) ----
__global__ void gatherfin2_kernel(const unsigned* __restrict__ sorted, const int* __restrict__ rowptr,
                                  const bf16* __restrict__ u2, const float* __restrict__ dinv,
                                  const float* __restrict__ b2, float* __restrict__ out, int N) {
    __shared__ float tile[64 * 16];
    __shared__ float sb2[16];
    if (threadIdx.x < 16) sb2[threadIdx.x] = b2[threadIdx.x];

    const unsigned* uvp = (const unsigned*)u2;
    GATHER_TILE(uvp)
    __syncthreads();

    int jj = threadIdx.x & 15;
    for (int rr = 0; rr < 4; rr++) {
        int rl = (threadIdx.x >> 4) + rr * 16;
        int node = blockIdx.x * 64 + rl;
        if (node >= N) continue;
        float di = dinv[node];
        float v = di * (tile[rl * 16 + jj] + __bfloat162float(u2[(size_t)node * H + jj])) + sb2[jj];

        float m = v;
#pragma unroll
        for (int off = 8; off >= 1; off >>= 1) m = fmaxf(m, __shfl_xor(m, off, 16));
        float ex = __expf(v - m);
        float s = ex;
#pragma unroll
        for (int off = 8; off >= 1; off >>= 1) s += __shfl_xor(s, off, 16);

        out[(size_t)node * H + jj] = v - m - __logf(s);
    }
}

extern "C" void kernel_launch(void* const* d_in, const int* in_sizes, int n_in,
                              void* d_out, int out_size, void* d_ws, size_t ws_size,
                              hipStream_t stream) {
    const float* x = (const float*)d_in[0];
    const int* edge_index = (const int*)d_in[1];
    const float* W1 = (const float*)d_in[2];
    const float* b1 = (const float*)d_in[3];
    const float* W2 = (const float*)d_in[4];
    const float* b2 = (const float*)d_in[5];
    float* out = (float*)d_out;

    const int N = in_sizes[0] / F_IN;        // 100000
    const int E = in_sizes[1] / 2;           // 3200000
    const int* src = edge_index;
    const int* dst = edge_index + E;
    const int NB = (N + NPB - 1) / NPB;      // 782

    // ws (4B units): dinv[N] | u[8N] | u2[8N] | packed[NB*SMAX] | sorted[E] |
    //                rowptr[N+1] | gcursor[NB] | base[NB+1]
    float* dinv = (float*)d_ws;
    bf16* u = (bf16*)(dinv + N);
    bf16* u2 = (bf16*)((unsigned*)u + (size_t)N * H / 2);
    unsigned* packed = (unsigned*)((unsigned*)u2 + (size_t)N * H / 2);
    unsigned* sorted = packed + (size_t)NB * SMAX;
    int* rowptr = (int*)(sorted + E);
    int* gcursor = rowptr + N + 1;
    int* base = gcursor + NB;

    hipMemsetAsync(gcursor, 0, NB * sizeof(int), stream);

    bin1_kernel<<<NBLK, BINT, 0, stream>>>(src, dst, gcursor, packed, E, NB);
    bucketscan_kernel<<<1, 1024, 0, stream>>>(gcursor, base, NB);
    sortcsr_kernel<<<NB, 512, 0, stream>>>(packed, gcursor, base, sorted, rowptr, dinv, N);

    xw1_kernel<<<(N + 15) / 16, 256, 0, stream>>>(x, W1, dinv, u, N);
    gatherfin1_kernel<<<(N + 63) / 64, 256, 0, stream>>>(sorted, rowptr, u, dinv, b1, W2, u2, N);
    gatherfin2_kernel<<<(N + 63) / 64, 256, 0, stream>>>(sorted, rowptr, u2, dinv, b2, out, N);
}